// Round 7
// baseline (309.327 us; speedup 1.0000x reference)
//
#include <hip/hip_runtime.h>

#define T_LEN 2048
#define C_DIM 768
#define NH 12
#define HD 64
#define B_SZ 4
#define M_ROWS (B_SZ * T_LEN)  // 8192
#define WSZ (C_DIM * C_DIM)    // 589824
#define CH 520                 // attn K LDS chunk stride (elements)

typedef __bf16 bf16x8 __attribute__((ext_vector_type(8)));
typedef float f32x4 __attribute__((ext_vector_type(4)));
typedef float f32x16 __attribute__((ext_vector_type(16)));

__device__ __forceinline__ unsigned short f2bf(float f) {
    union { __bf16 b; unsigned short u; } c;
    c.b = (__bf16)f;
    return c.u;
}
__device__ __forceinline__ unsigned pk2bf(float a, float b) {
    return (unsigned)f2bf(a) | ((unsigned)f2bf(b) << 16);
}

__device__ __forceinline__ float fast_exp2(float x) {
    float r;
    asm("v_exp_f32 %0, %1" : "=v"(r) : "v"(x));
    return r;
}

// async global->LDS, 16B/lane; LDS dest = uniform base + lane*16.
__device__ __forceinline__ void gl2lds16(const void* g, void* l) {
    __builtin_amdgcn_global_load_lds(
        (const __attribute__((address_space(1))) unsigned int*)g,
        (__attribute__((address_space(3))) unsigned int*)l, 16, 0, 0);
}

// ---------------------------------------------------------------------------
// Fused prep: blocks [0,6144): x fp32 -> bf16. Blocks [6144,8448): W -> Wt
// (bf16 W^T per slab z).
// ---------------------------------------------------------------------------
__global__ __launch_bounds__(256) void prep(
    const float* __restrict__ x, const float* __restrict__ W0,
    const float* __restrict__ W1, const float* __restrict__ W2,
    const float* __restrict__ W3, unsigned short* __restrict__ xb,
    unsigned short* __restrict__ WtAll)
{
    __shared__ float tile[32][33];
    if (blockIdx.x < 6144) {
        const int i = blockIdx.x * 256 + threadIdx.x;
        float4 v = ((const float4*)x)[i];
        ushort4 o;
        o.x = f2bf(v.x); o.y = f2bf(v.y); o.z = f2bf(v.z); o.w = f2bf(v.w);
        ((ushort4*)xb)[i] = o;
    } else {
        const int wi = blockIdx.x - 6144;
        const int z = wi / 576, rem = wi % 576;
        const int k0 = (rem / 24) * 32, n0 = (rem % 24) * 32;
        const float* W = (z == 0) ? W0 : (z == 1) ? W1 : (z == 2) ? W2 : W3;
        unsigned short* out = WtAll + (size_t)z * WSZ;
        const int r = threadIdx.x >> 3, c4 = (threadIdx.x & 7) * 4;
        float4 v = *(const float4*)&W[(size_t)(k0 + r) * C_DIM + n0 + c4];
        tile[r][c4 + 0] = v.x;
        tile[r][c4 + 1] = v.y;
        tile[r][c4 + 2] = v.z;
        tile[r][c4 + 3] = v.w;
        __syncthreads();
        ushort4 o;
        o.x = f2bf(tile[c4 + 0][r]);
        o.y = f2bf(tile[c4 + 1][r]);
        o.z = f2bf(tile[c4 + 2][r]);
        o.w = f2bf(tile[c4 + 3][r]);
        *(ushort4*)&out[(size_t)(n0 + r) * C_DIM + k0 + c4] = o;
    }
}

// ---------------------------------------------------------------------------
// bf16 MFMA GEMM: 128x128 tile, 4 waves (2x2 of 64x64), 4x4 of 16x16x32.
// A staged via dbuf global_load_lds; B-fragments loaded DIRECT from global
// (Wt rows match the B-operand lane layout) with a register double-buffer —
// halves LDS traffic, frees Bs.
// mode 0 (z 0..2): q (pre-scaled 0.125/ln2) / k bf16 [bh][t][d], v [bh][d][t]
// mode 1: fp32 [m][768] + bias
// ---------------------------------------------------------------------------
__global__ __launch_bounds__(256) void gemm_bf16(
    const unsigned short* __restrict__ A, const unsigned short* __restrict__ WtAll,
    const float* __restrict__ b0, const float* __restrict__ b1,
    const float* __restrict__ b2,
    unsigned short* __restrict__ qg, unsigned short* __restrict__ kg,
    unsigned short* __restrict__ vtg, float* __restrict__ outF, int mode)
{
    __shared__ __align__(16) unsigned short As[2][8 * 512];
    const int tid = threadIdx.x;
    const int lane = tid & 63, w = tid >> 6;
    const int L15 = lane & 15, quad = lane >> 4;
    const int m0 = blockIdx.x * 128, n0 = blockIdx.y * 128;
    const int z = blockIdx.z;
    const unsigned short* W = WtAll + (size_t)z * WSZ;

    const int c0 = 2 * w, c1 = 2 * w + 1;
    const size_t aOff0 = (size_t)(m0 + c0 * 16 + L15) * C_DIM + quad * 8;
    const size_t aOff1 = (size_t)(m0 + c1 * 16 + L15) * C_DIM + quad * 8;
    const int cm = (w >> 1) * 4, cn = (w & 1) * 4;
    size_t bOff[4];
#pragma unroll
    for (int j = 0; j < 4; j++)
        bOff[j] = (size_t)(n0 + (cn + j) * 16 + L15) * C_DIM + quad * 8;

    f32x4 acc[4][4];
#pragma unroll
    for (int i = 0; i < 4; i++)
#pragma unroll
        for (int j = 0; j < 4; j++) acc[i][j] = 0.0f;

    bf16x8 bF[2][4];
#pragma unroll
    for (int j = 0; j < 4; j++) bF[0][j] = *(const bf16x8*)&W[bOff[j]];
    gl2lds16(&A[aOff0], &As[0][c0 * 512]);
    gl2lds16(&A[aOff1], &As[0][c1 * 512]);
    __syncthreads();

    for (int kt = 0; kt < 24; kt++) {
        const int cur = kt & 1;
        if (kt < 23) {
            const size_t o = (size_t)(kt + 1) * 32;
            gl2lds16(&A[aOff0 + o], &As[cur ^ 1][c0 * 512]);
            gl2lds16(&A[aOff1 + o], &As[cur ^ 1][c1 * 512]);
#pragma unroll
            for (int j = 0; j < 4; j++)
                bF[cur ^ 1][j] = *(const bf16x8*)&W[bOff[j] + o];
        }
        bf16x8 aF[4];
#pragma unroll
        for (int i = 0; i < 4; i++)
            aF[i] = *(const bf16x8*)&As[cur][(cm + i) * 512 + lane * 8];
#pragma unroll
        for (int i = 0; i < 4; i++)
#pragma unroll
            for (int j = 0; j < 4; j++)
                acc[i][j] = __builtin_amdgcn_mfma_f32_16x16x32_bf16(
                    aF[i], bF[cur][j], acc[i][j], 0, 0, 0);
        __syncthreads();
    }

    const float* bias = (mode == 0) ? ((z == 0) ? b0 : (z == 1) ? b1 : b2) : b0;
    // Q pre-scale folds 1/sqrt(64) and 1/ln(2) (attn exponentiates base-2)
    const float qscale = (z == 0 && mode == 0) ? 0.18033688011112042f : 1.0f;
#pragma unroll
    for (int i = 0; i < 4; i++) {
        const int mBase = m0 + (w >> 1) * 64 + i * 16 + quad * 4;
#pragma unroll
        for (int j = 0; j < 4; j++) {
            const int n = n0 + (w & 1) * 64 + j * 16 + L15;
            const float bn = bias[n];
            if (mode == 0) {
                const int h = n >> 6, d = n & 63;
                const int b = mBase >> 11, tB = mBase & (T_LEN - 1);
                if (z < 2) {
                    unsigned short* o = (z == 0) ? qg : kg;
#pragma unroll
                    for (int r = 0; r < 4; r++)
                        o[(((size_t)(b * NH + h)) * T_LEN + tB + r) * HD + d] =
                            f2bf((acc[i][j][r] + bn) * qscale);
                } else {
                    ushort4 o4;
                    o4.x = f2bf(acc[i][j][0] + bn);
                    o4.y = f2bf(acc[i][j][1] + bn);
                    o4.z = f2bf(acc[i][j][2] + bn);
                    o4.w = f2bf(acc[i][j][3] + bn);
                    *(ushort4*)&vtg[(((size_t)(b * NH + h)) * HD + d) * T_LEN + tB] = o4;
                }
            } else {
#pragma unroll
                for (int r = 0; r < 4; r++)
                    outF[(size_t)(mBase + r) * C_DIM + n] = acc[i][j][r] + bn;
            }
        }
    }
}

// ---------------------------------------------------------------------------
// MFMA flash attention, transposed-score, 64 q per wave (2 n-tiles of 32),
// 2 waves = 128 q per block. K staged via dbuf global_load_lds (frags shared
// across both n-tiles); V^T fragments DIRECT from global (issued before the
// K stage so their vmcnt waits don't drain the prefetch). No-max softmax
// (p = 2^s, Q pre-scaled 0.125/ln2); register P-transpose (shfl_xor 32).
// ---------------------------------------------------------------------------
__global__ __launch_bounds__(128, 2) void attn_mfma(
    const unsigned short* __restrict__ qg, const unsigned short* __restrict__ kg,
    const unsigned short* __restrict__ vtg, unsigned short* __restrict__ attb)
{
    __shared__ __align__(16) unsigned short Ks[2][8 * CH];
    const int tid = threadIdx.x;
    const int lane = tid & 63, w = tid >> 6;  // w in 0..1
    const int L15 = lane & 15, L31 = lane & 31;
    const int quad = lane >> 4, r4 = (lane >> 4) & 1, r5 = lane >> 5;

    // LPT: heaviest q-tiles dispatch first
    const int n = blockIdx.x;
    const int qi = 15 - (n / (B_SZ * NH));
    const int bh = n % (B_SZ * NH);
    const size_t base = (size_t)bh * T_LEN * HD;
    const int q0 = qi * 128;
    const int nk = 2 * qi + 2;

    // Q fragments (B-operand) for the wave's two 32-q n-tiles
    bf16x8 qf[2][4];
#pragma unroll
    for (int t = 0; t < 2; t++)
#pragma unroll
        for (int kc = 0; kc < 4; kc++)
            qf[t][kc] = *(const bf16x8*)&qg[base +
                (size_t)(q0 + w * 64 + t * 32 + L31) * HD + kc * 16 + r5 * 8];

    f32x16 accO[2][2];
#pragma unroll
    for (int t = 0; t < 2; t++)
#pragma unroll
        for (int md = 0; md < 2; md++) accO[t][md] = 0.0f;
    float l[2] = {0.0f, 0.0f};

    auto stage = [&](int kt, int buf) {
        const int ktb = kt * 64;
#pragma unroll
        for (int c = 0; c < 2; c++) {
            const int rg = 2 * w + c;
            gl2lds16(&kg[base + (size_t)(ktb + rg * 16 + L15) * HD + quad * 8],
                     &Ks[buf][(rg * 2) * CH]);
            gl2lds16(&kg[base + (size_t)(ktb + rg * 16 + L15) * HD + 32 + quad * 8],
                     &Ks[buf][(rg * 2 + 1) * CH]);
        }
    };

    stage(0, 0);
    __syncthreads();

    const int qmaxw = q0 + w * 64 + 63;

    for (int kt = 0; kt < nk; kt++) {
        const int cur = kt & 1;
        const int ktb = kt * 64;
        const bool active = (ktb <= qmaxw);
        // V^T fragments direct from global — issue BEFORE the K stage so
        // waiting on them leaves the stage loads in flight.
        bf16x8 vf[2][4];
        if (active) {
#pragma unroll
            for (int md = 0; md < 2; md++)
#pragma unroll
                for (int kc = 0; kc < 4; kc++)
                    vf[md][kc] = *(const bf16x8*)&vtg[base +
                        (size_t)(md * 32 + L31) * T_LEN + ktb + kc * 16 + r5 * 8];
        }
        if (kt + 1 < nk) stage(kt + 1, cur ^ 1);

        if (active) {
            bf16x8 pf[2][4];
#pragma unroll
            for (int mi = 0; mi < 2; mi++) {
                bf16x8 kf[4];
#pragma unroll
                for (int kc = 0; kc < 4; kc++)
                    kf[kc] = *(const bf16x8*)&Ks[cur][
                        (mi * 4 + r4 * 2 + (kc >> 1)) * CH +
                        (L15 + 16 * ((kc & 1) * 2 + r5)) * 8];
                f32x16 sa[2];
#pragma unroll
                for (int t = 0; t < 2; t++) {
                    sa[t] = 0.0f;
#pragma unroll
                    for (int kc = 0; kc < 4; kc++)
                        sa[t] = __builtin_amdgcn_mfma_f32_32x32x16_bf16(
                            kf[kc], qf[t][kc], sa[t], 0, 0, 0);
                }
#pragma unroll
                for (int t = 0; t < 2; t++) {
                    const int qrow = q0 + w * 64 + t * 32 + L31;
                    const bool needmask = (ktb + mi * 32 + 31 > q0 + w * 64 + t * 32);
                    uint2 pk[4];
#pragma unroll
                    for (int g = 0; g < 4; g++) {
                        float p[4];
#pragma unroll
                        for (int rr = 0; rr < 4; rr++) {
                            float s = sa[t][g * 4 + rr];
                            if (needmask) {
                                const int key = ktb + mi * 32 + 8 * g + 4 * r5 + rr;
                                s = (key <= qrow) ? s : -1e30f;
                            }
                            p[rr] = fast_exp2(s);
                            l[t] += p[rr];
                        }
                        pk[g].x = pk2bf(p[0], p[1]);
                        pk[g].y = pk2bf(p[2], p[3]);
                    }
                    // register P-transpose: partner (lane^32) holds the
                    // complementary key packs
                    uint2 z1, z2, x1, x2;
                    z1.x = r5 ? pk[0].x : pk[1].x;
                    z1.y = r5 ? pk[0].y : pk[1].y;
                    z2.x = r5 ? pk[2].x : pk[3].x;
                    z2.y = r5 ? pk[2].y : pk[3].y;
                    x1.x = (unsigned)__shfl_xor((int)z1.x, 32, 64);
                    x1.y = (unsigned)__shfl_xor((int)z1.y, 32, 64);
                    x2.x = (unsigned)__shfl_xor((int)z2.x, 32, 64);
                    x2.y = (unsigned)__shfl_xor((int)z2.y, 32, 64);
                    union { bf16x8 v; unsigned u[4]; } f0, f1;
                    f0.u[0] = r5 ? x1.x : pk[0].x;
                    f0.u[1] = r5 ? x1.y : pk[0].y;
                    f0.u[2] = r5 ? pk[1].x : x1.x;
                    f0.u[3] = r5 ? pk[1].y : x1.y;
                    f1.u[0] = r5 ? x2.x : pk[2].x;
                    f1.u[1] = r5 ? x2.y : pk[2].y;
                    f1.u[2] = r5 ? pk[3].x : x2.x;
                    f1.u[3] = r5 ? pk[3].y : x2.y;
                    pf[t][mi * 2] = f0.v;
                    pf[t][mi * 2 + 1] = f1.v;
                }
            }
            // ---- O^T += V^T · P^T ----
#pragma unroll
            for (int md = 0; md < 2; md++)
#pragma unroll
                for (int kc = 0; kc < 4; kc++)
#pragma unroll
                    for (int t = 0; t < 2; t++)
                        accO[t][md] = __builtin_amdgcn_mfma_f32_32x32x16_bf16(
                            vf[md][kc], pf[t][kc], accO[t][md], 0, 0, 0);
        }
        __syncthreads();
    }

    // ---- epilogue: l reduce (r5 pair per q), normalize, store bf16 ----
    const int b = bh / NH, h = bh % NH;
#pragma unroll
    for (int t = 0; t < 2; t++) {
        const float lt = l[t] + __shfl_xor(l[t], 32, 64);
        const float inv = __builtin_amdgcn_rcpf(lt);
        const int qrow = q0 + w * 64 + t * 32 + L31;
        const size_t orow = ((size_t)(b * T_LEN + qrow)) * C_DIM + h * HD;
#pragma unroll
        for (int md = 0; md < 2; md++) {
#pragma unroll
            for (int g = 0; g < 4; g++) {
                uint2 wv;
                wv.x = pk2bf(accO[t][md][g * 4 + 0] * inv,
                             accO[t][md][g * 4 + 1] * inv);
                wv.y = pk2bf(accO[t][md][g * 4 + 2] * inv,
                             accO[t][md][g * 4 + 3] * inv);
                *(uint2*)&attb[orow + md * 32 + 8 * g + 4 * r5] = wv;
            }
        }
    }
}

extern "C" void kernel_launch(void* const* d_in, const int* in_sizes, int n_in,
                              void* d_out, int out_size, void* d_ws, size_t ws_size,
                              hipStream_t stream)
{
    const float* x  = (const float*)d_in[0];
    const float* Wq = (const float*)d_in[1];
    const float* bq = (const float*)d_in[2];
    const float* Wk = (const float*)d_in[3];
    const float* bk = (const float*)d_in[4];
    const float* Wv = (const float*)d_in[5];
    const float* bv = (const float*)d_in[6];
    const float* Wo = (const float*)d_in[7];
    const float* bo = (const float*)d_in[8];
    float* out = (float*)d_out;

    const size_t nMC = (size_t)M_ROWS * C_DIM;  // 6291456
    unsigned short* xb   = (unsigned short*)d_ws;
    unsigned short* Wt   = xb + nMC;
    unsigned short* qg   = Wt + 4 * (size_t)WSZ;
    unsigned short* kg   = qg + nMC;
    unsigned short* vtg  = kg + nMC;
    unsigned short* attb = vtg + nMC;

    prep<<<6144 + 2304, 256, 0, stream>>>(x, Wq, Wk, Wv, Wo, xb, Wt);
    gemm_bf16<<<dim3(64, 6, 3), 256, 0, stream>>>(xb, Wt, bq, bk, bv,
                                                  qg, kg, vtg, nullptr, 0);
    attn_mfma<<<16 * B_SZ * NH, 128, 0, stream>>>(qg, kg, vtg, attb);
    gemm_bf16<<<dim3(64, 6, 1), 256, 0, stream>>>(attb, Wt + 3 * (size_t)WSZ,
                                                  bo, bo, bo, nullptr, nullptr,
                                                  nullptr, out, 1);
}

// Round 8
// 281.309 us; speedup vs baseline: 1.0996x; 1.0996x over previous
//
#include <hip/hip_runtime.h>

#define T_LEN 2048
#define C_DIM 768
#define NH 12
#define HD 64
#define B_SZ 4
#define M_ROWS (B_SZ * T_LEN)  // 8192
#define WSZ (C_DIM * C_DIM)    // 589824
#define CH 520                 // attn K LDS chunk stride (elements)

typedef __bf16 bf16x8 __attribute__((ext_vector_type(8)));
typedef float f32x4 __attribute__((ext_vector_type(4)));
typedef float f32x16 __attribute__((ext_vector_type(16)));

__device__ __forceinline__ unsigned short f2bf(float f) {
    union { __bf16 b; unsigned short u; } c;
    c.b = (__bf16)f;
    return c.u;
}
__device__ __forceinline__ unsigned pk2bf(float a, float b) {
    return (unsigned)f2bf(a) | ((unsigned)f2bf(b) << 16);
}

__device__ __forceinline__ float fast_exp2(float x) {
    float r;
    asm("v_exp_f32 %0, %1" : "=v"(r) : "v"(x));
    return r;
}

// async global->LDS, 16B/lane; LDS dest = uniform base + lane*16.
__device__ __forceinline__ void gl2lds16(const void* g, void* l) {
    __builtin_amdgcn_global_load_lds(
        (const __attribute__((address_space(1))) unsigned int*)g,
        (__attribute__((address_space(3))) unsigned int*)l, 16, 0, 0);
}

// ---------------------------------------------------------------------------
// Fused prep: blocks [0,6144): x fp32 -> bf16. Blocks [6144,8448): W -> Wt
// (bf16 W^T per slab z).
// ---------------------------------------------------------------------------
__global__ __launch_bounds__(256) void prep(
    const float* __restrict__ x, const float* __restrict__ W0,
    const float* __restrict__ W1, const float* __restrict__ W2,
    const float* __restrict__ W3, unsigned short* __restrict__ xb,
    unsigned short* __restrict__ WtAll)
{
    __shared__ float tile[32][33];
    if (blockIdx.x < 6144) {
        const int i = blockIdx.x * 256 + threadIdx.x;
        float4 v = ((const float4*)x)[i];
        ushort4 o;
        o.x = f2bf(v.x); o.y = f2bf(v.y); o.z = f2bf(v.z); o.w = f2bf(v.w);
        ((ushort4*)xb)[i] = o;
    } else {
        const int wi = blockIdx.x - 6144;
        const int z = wi / 576, rem = wi % 576;
        const int k0 = (rem / 24) * 32, n0 = (rem % 24) * 32;
        const float* W = (z == 0) ? W0 : (z == 1) ? W1 : (z == 2) ? W2 : W3;
        unsigned short* out = WtAll + (size_t)z * WSZ;
        const int r = threadIdx.x >> 3, c4 = (threadIdx.x & 7) * 4;
        float4 v = *(const float4*)&W[(size_t)(k0 + r) * C_DIM + n0 + c4];
        tile[r][c4 + 0] = v.x;
        tile[r][c4 + 1] = v.y;
        tile[r][c4 + 2] = v.z;
        tile[r][c4 + 3] = v.w;
        __syncthreads();
        ushort4 o;
        o.x = f2bf(tile[c4 + 0][r]);
        o.y = f2bf(tile[c4 + 1][r]);
        o.z = f2bf(tile[c4 + 2][r]);
        o.w = f2bf(tile[c4 + 3][r]);
        *(ushort4*)&out[(size_t)(n0 + r) * C_DIM + k0 + c4] = o;
    }
}

// ---------------------------------------------------------------------------
// bf16 MFMA GEMM (Round-6 proven config): 128x128 tile, 4 waves (2x2 of
// 64x64), 4x4 of 16x16x32 per wave, double-buffered global_load_lds staging
// of BOTH A and B, one barrier per K-iter.
// mode 0 (z 0..2): q (pre-scaled 0.125/ln2) / k bf16 [bh][t][d], v [bh][d][t]
// mode 1: fp32 [m][768] + bias
// ---------------------------------------------------------------------------
__global__ __launch_bounds__(256) void gemm_bf16(
    const unsigned short* __restrict__ A, const unsigned short* __restrict__ WtAll,
    const float* __restrict__ b0, const float* __restrict__ b1,
    const float* __restrict__ b2,
    unsigned short* __restrict__ qg, unsigned short* __restrict__ kg,
    unsigned short* __restrict__ vtg, float* __restrict__ outF, int mode)
{
    __shared__ __align__(16) unsigned short As[2][8 * 512];
    __shared__ __align__(16) unsigned short Bs[2][8 * 512];
    const int tid = threadIdx.x;
    const int lane = tid & 63, w = tid >> 6;
    const int L15 = lane & 15, quad = lane >> 4;
    const int m0 = blockIdx.x * 128, n0 = blockIdx.y * 128;
    const int z = blockIdx.z;
    const unsigned short* W = WtAll + (size_t)z * WSZ;

    const int c0 = 2 * w, c1 = 2 * w + 1;
    const size_t aOff0 = (size_t)(m0 + c0 * 16 + L15) * C_DIM + quad * 8;
    const size_t aOff1 = (size_t)(m0 + c1 * 16 + L15) * C_DIM + quad * 8;
    const size_t bOff0 = (size_t)(n0 + c0 * 16 + L15) * C_DIM + quad * 8;
    const size_t bOff1 = (size_t)(n0 + c1 * 16 + L15) * C_DIM + quad * 8;

    f32x4 acc[4][4];
#pragma unroll
    for (int i = 0; i < 4; i++)
#pragma unroll
        for (int j = 0; j < 4; j++) acc[i][j] = 0.0f;

    const int cm = (w >> 1) * 4, cn = (w & 1) * 4;

    gl2lds16(&A[aOff0], &As[0][c0 * 512]);
    gl2lds16(&A[aOff1], &As[0][c1 * 512]);
    gl2lds16(&W[bOff0], &Bs[0][c0 * 512]);
    gl2lds16(&W[bOff1], &Bs[0][c1 * 512]);
    __syncthreads();

    for (int kt = 0; kt < 24; kt++) {
        const int cur = kt & 1;
        if (kt < 23) {
            const size_t o = (size_t)(kt + 1) * 32;
            gl2lds16(&A[aOff0 + o], &As[cur ^ 1][c0 * 512]);
            gl2lds16(&A[aOff1 + o], &As[cur ^ 1][c1 * 512]);
            gl2lds16(&W[bOff0 + o], &Bs[cur ^ 1][c0 * 512]);
            gl2lds16(&W[bOff1 + o], &Bs[cur ^ 1][c1 * 512]);
        }
        bf16x8 aF[4], bF[4];
#pragma unroll
        for (int i = 0; i < 4; i++)
            aF[i] = *(const bf16x8*)&As[cur][(cm + i) * 512 + lane * 8];
#pragma unroll
        for (int j = 0; j < 4; j++)
            bF[j] = *(const bf16x8*)&Bs[cur][(cn + j) * 512 + lane * 8];
#pragma unroll
        for (int i = 0; i < 4; i++)
#pragma unroll
            for (int j = 0; j < 4; j++)
                acc[i][j] = __builtin_amdgcn_mfma_f32_16x16x32_bf16(
                    aF[i], bF[j], acc[i][j], 0, 0, 0);
        __syncthreads();
    }

    const float* bias = (mode == 0) ? ((z == 0) ? b0 : (z == 1) ? b1 : b2) : b0;
    // Q pre-scale folds 1/sqrt(64) and 1/ln(2) (attn exponentiates base-2)
    const float qscale = (z == 0 && mode == 0) ? 0.18033688011112042f : 1.0f;
#pragma unroll
    for (int i = 0; i < 4; i++) {
        const int mBase = m0 + (w >> 1) * 64 + i * 16 + quad * 4;
#pragma unroll
        for (int j = 0; j < 4; j++) {
            const int n = n0 + (w & 1) * 64 + j * 16 + L15;
            const float bn = bias[n];
            if (mode == 0) {
                const int h = n >> 6, d = n & 63;
                const int b = mBase >> 11, tB = mBase & (T_LEN - 1);
                if (z < 2) {
                    unsigned short* o = (z == 0) ? qg : kg;
#pragma unroll
                    for (int r = 0; r < 4; r++)
                        o[(((size_t)(b * NH + h)) * T_LEN + tB + r) * HD + d] =
                            f2bf((acc[i][j][r] + bn) * qscale);
                } else {
                    ushort4 o4;
                    o4.x = f2bf(acc[i][j][0] + bn);
                    o4.y = f2bf(acc[i][j][1] + bn);
                    o4.z = f2bf(acc[i][j][2] + bn);
                    o4.w = f2bf(acc[i][j][3] + bn);
                    *(ushort4*)&vtg[(((size_t)(b * NH + h)) * HD + d) * T_LEN + tB] = o4;
                }
            } else {
#pragma unroll
                for (int r = 0; r < 4; r++)
                    outF[(size_t)(mBase + r) * C_DIM + n] = acc[i][j][r] + bn;
            }
        }
    }
}

// ---------------------------------------------------------------------------
// MFMA flash attention (R6 structure + V-direct). 4 waves x 32 q = 128 q per
// block, 256 threads, grid 768. K staged via dbuf global_load_lds; V^T
// fragments DIRECT from global (all 4 waves read the same 8KB tile -> L1;
// issued before the K prefetch so their vmcnt wait leaves it in flight).
// No-max softmax (p = 2^s, Q pre-scaled 0.125/ln2); register P-transpose.
// ---------------------------------------------------------------------------
__global__ __launch_bounds__(256) void attn_mfma(
    const unsigned short* __restrict__ qg, const unsigned short* __restrict__ kg,
    const unsigned short* __restrict__ vtg, unsigned short* __restrict__ attb)
{
    __shared__ __align__(16) unsigned short Ks[2][8 * CH];
    const int tid = threadIdx.x;
    const int lane = tid & 63, w = tid >> 6;
    const int L15 = lane & 15, L31 = lane & 31;
    const int quad = lane >> 4, r4 = (lane >> 4) & 1, r5 = lane >> 5;

    // LPT: heaviest q-tiles dispatch first
    const int n = blockIdx.x;
    const int qi = 15 - (n / (B_SZ * NH));
    const int bh = n % (B_SZ * NH);
    const size_t base = (size_t)bh * T_LEN * HD;
    const int q0 = qi * 128;
    const int nk = 2 * qi + 2;
    const int qrow = q0 + w * 32 + L31;

    // Q fragments (B-operand): n=q on lane&31, k = r5*8+j per 16-d chunk
    bf16x8 qf[4];
#pragma unroll
    for (int kc = 0; kc < 4; kc++)
        qf[kc] = *(const bf16x8*)&qg[base + (size_t)qrow * HD + kc * 16 + r5 * 8];

    f32x16 accO[2];
#pragma unroll
    for (int md = 0; md < 2; md++) accO[md] = 0.0f;
    float l = 0.0f;

    auto stage = [&](int kt, int buf) {
        const int ktb = kt * 64;
        gl2lds16(&kg[base + (size_t)(ktb + w * 16 + L15) * HD + quad * 8],
                 &Ks[buf][(2 * w) * CH]);
        gl2lds16(&kg[base + (size_t)(ktb + w * 16 + L15) * HD + 32 + quad * 8],
                 &Ks[buf][(2 * w + 1) * CH]);
    };

    stage(0, 0);
    __syncthreads();

    const int qmaxw = q0 + w * 32 + 31;
    const int qminw = q0 + w * 32;

    for (int kt = 0; kt < nk; kt++) {
        const int cur = kt & 1;
        const int ktb = kt * 64;
        const bool active = (ktb <= qmaxw);
        // V^T fragments direct from global — issued BEFORE the K prefetch
        bf16x8 vf[2][4];
        if (active) {
#pragma unroll
            for (int md = 0; md < 2; md++)
#pragma unroll
                for (int kc = 0; kc < 4; kc++)
                    vf[md][kc] = *(const bf16x8*)&vtg[base +
                        (size_t)(md * 32 + L31) * T_LEN + ktb + kc * 16 + r5 * 8];
        }
        if (kt + 1 < nk) stage(kt + 1, cur ^ 1);

        if (active) {
            bf16x8 pf[4];
#pragma unroll
            for (int mi = 0; mi < 2; mi++) {
                bf16x8 kf[4];
#pragma unroll
                for (int kc = 0; kc < 4; kc++)
                    kf[kc] = *(const bf16x8*)&Ks[cur][
                        (mi * 4 + r4 * 2 + (kc >> 1)) * CH +
                        (L15 + 16 * ((kc & 1) * 2 + r5)) * 8];
                f32x16 sa;
                sa = 0.0f;
#pragma unroll
                for (int kc = 0; kc < 4; kc++)
                    sa = __builtin_amdgcn_mfma_f32_32x32x16_bf16(
                        kf[kc], qf[kc], sa, 0, 0, 0);

                const bool needmask = (ktb + mi * 32 + 31 > qminw);
                uint2 pk[4];
#pragma unroll
                for (int g = 0; g < 4; g++) {
                    float p[4];
#pragma unroll
                    for (int rr = 0; rr < 4; rr++) {
                        float s = sa[g * 4 + rr];
                        if (needmask) {
                            const int key = ktb + mi * 32 + 8 * g + 4 * r5 + rr;
                            s = (key <= qrow) ? s : -1e30f;
                        }
                        p[rr] = fast_exp2(s);
                        l += p[rr];
                    }
                    pk[g].x = pk2bf(p[0], p[1]);
                    pk[g].y = pk2bf(p[2], p[3]);
                }
                // register P-transpose: partner (lane^32) holds complementary packs
                uint2 z1, z2, x1, x2;
                z1.x = r5 ? pk[0].x : pk[1].x;
                z1.y = r5 ? pk[0].y : pk[1].y;
                z2.x = r5 ? pk[2].x : pk[3].x;
                z2.y = r5 ? pk[2].y : pk[3].y;
                x1.x = (unsigned)__shfl_xor((int)z1.x, 32, 64);
                x1.y = (unsigned)__shfl_xor((int)z1.y, 32, 64);
                x2.x = (unsigned)__shfl_xor((int)z2.x, 32, 64);
                x2.y = (unsigned)__shfl_xor((int)z2.y, 32, 64);
                union { bf16x8 v; unsigned u[4]; } f0, f1;
                f0.u[0] = r5 ? x1.x : pk[0].x;
                f0.u[1] = r5 ? x1.y : pk[0].y;
                f0.u[2] = r5 ? pk[1].x : x1.x;
                f0.u[3] = r5 ? pk[1].y : x1.y;
                f1.u[0] = r5 ? x2.x : pk[2].x;
                f1.u[1] = r5 ? x2.y : pk[2].y;
                f1.u[2] = r5 ? pk[3].x : x2.x;
                f1.u[3] = r5 ? pk[3].y : x2.y;
                pf[mi * 2] = f0.v;
                pf[mi * 2 + 1] = f1.v;
            }
            // ---- O^T += V^T · P^T ----
#pragma unroll
            for (int md = 0; md < 2; md++)
#pragma unroll
                for (int kc = 0; kc < 4; kc++)
                    accO[md] = __builtin_amdgcn_mfma_f32_32x32x16_bf16(
                        vf[md][kc], pf[kc], accO[md], 0, 0, 0);
        }
        __syncthreads();
    }

    // ---- epilogue: l reduce (r5 pair per q), normalize, store bf16 ----
    const float lt = l + __shfl_xor(l, 32, 64);
    const float inv = __builtin_amdgcn_rcpf(lt);
    const int b = bh / NH, h = bh % NH;
    const size_t orow = ((size_t)(b * T_LEN + qrow)) * C_DIM + h * HD;
#pragma unroll
    for (int md = 0; md < 2; md++) {
#pragma unroll
        for (int g = 0; g < 4; g++) {
            uint2 wv;
            wv.x = pk2bf(accO[md][g * 4 + 0] * inv, accO[md][g * 4 + 1] * inv);
            wv.y = pk2bf(accO[md][g * 4 + 2] * inv, accO[md][g * 4 + 3] * inv);
            *(uint2*)&attb[orow + md * 32 + 8 * g + 4 * r5] = wv;
        }
    }
}

extern "C" void kernel_launch(void* const* d_in, const int* in_sizes, int n_in,
                              void* d_out, int out_size, void* d_ws, size_t ws_size,
                              hipStream_t stream)
{
    const float* x  = (const float*)d_in[0];
    const float* Wq = (const float*)d_in[1];
    const float* bq = (const float*)d_in[2];
    const float* Wk = (const float*)d_in[3];
    const float* bk = (const float*)d_in[4];
    const float* Wv = (const float*)d_in[5];
    const float* bv = (const float*)d_in[6];
    const float* Wo = (const float*)d_in[7];
    const float* bo = (const float*)d_in[8];
    float* out = (float*)d_out;

    const size_t nMC = (size_t)M_ROWS * C_DIM;  // 6291456
    unsigned short* xb   = (unsigned short*)d_ws;
    unsigned short* Wt   = xb + nMC;
    unsigned short* qg   = Wt + 4 * (size_t)WSZ;
    unsigned short* kg   = qg + nMC;
    unsigned short* vtg  = kg + nMC;
    unsigned short* attb = vtg + nMC;

    prep<<<6144 + 2304, 256, 0, stream>>>(x, Wq, Wk, Wv, Wo, xb, Wt);
    gemm_bf16<<<dim3(64, 6, 3), 256, 0, stream>>>(xb, Wt, bq, bk, bv,
                                                  qg, kg, vtg, nullptr, 0);
    attn_mfma<<<16 * B_SZ * NH, 256, 0, stream>>>(qg, kg, vtg, attb);
    gemm_bf16<<<dim3(64, 6, 1), 256, 0, stream>>>(attb, Wt + 3 * (size_t)WSZ,
                                                  bo, bo, bo, nullptr, nullptr,
                                                  nullptr, out, 1);
}

// Round 9
// 257.456 us; speedup vs baseline: 1.2015x; 1.0926x over previous
//
#include <hip/hip_runtime.h>

#define T_LEN 2048
#define C_DIM 768
#define NH 12
#define HD 64
#define B_SZ 4
#define M_ROWS (B_SZ * T_LEN)  // 8192
#define WSZ (C_DIM * C_DIM)    // 589824
#define CH 520                 // attn K/V LDS chunk stride (elements)

typedef __bf16 bf16x8 __attribute__((ext_vector_type(8)));
typedef float f32x4 __attribute__((ext_vector_type(4)));
typedef float f32x16 __attribute__((ext_vector_type(16)));

__device__ __forceinline__ unsigned short f2bf(float f) {
    union { __bf16 b; unsigned short u; } c;
    c.b = (__bf16)f;
    return c.u;
}
__device__ __forceinline__ unsigned pk2bf(float a, float b) {
    return (unsigned)f2bf(a) | ((unsigned)f2bf(b) << 16);
}

__device__ __forceinline__ float fast_exp2(float x) {
    float r;
    asm("v_exp_f32 %0, %1" : "=v"(r) : "v"(x));
    return r;
}

// async global->LDS, 16B/lane; LDS dest = uniform base + lane*16.
__device__ __forceinline__ void gl2lds16(const void* g, void* l) {
    __builtin_amdgcn_global_load_lds(
        (const __attribute__((address_space(1))) unsigned int*)g,
        (__attribute__((address_space(3))) unsigned int*)l, 16, 0, 0);
}

// ---------------------------------------------------------------------------
// Fused prep: blocks [0,6144): x fp32 -> bf16. Blocks [6144,8448): W -> Wt
// (bf16 W^T per slab z).
// ---------------------------------------------------------------------------
__global__ __launch_bounds__(256) void prep(
    const float* __restrict__ x, const float* __restrict__ W0,
    const float* __restrict__ W1, const float* __restrict__ W2,
    const float* __restrict__ W3, unsigned short* __restrict__ xb,
    unsigned short* __restrict__ WtAll)
{
    __shared__ float tile[32][33];
    if (blockIdx.x < 6144) {
        const int i = blockIdx.x * 256 + threadIdx.x;
        float4 v = ((const float4*)x)[i];
        ushort4 o;
        o.x = f2bf(v.x); o.y = f2bf(v.y); o.z = f2bf(v.z); o.w = f2bf(v.w);
        ((ushort4*)xb)[i] = o;
    } else {
        const int wi = blockIdx.x - 6144;
        const int z = wi / 576, rem = wi % 576;
        const int k0 = (rem / 24) * 32, n0 = (rem % 24) * 32;
        const float* W = (z == 0) ? W0 : (z == 1) ? W1 : (z == 2) ? W2 : W3;
        unsigned short* out = WtAll + (size_t)z * WSZ;
        const int r = threadIdx.x >> 3, c4 = (threadIdx.x & 7) * 4;
        float4 v = *(const float4*)&W[(size_t)(k0 + r) * C_DIM + n0 + c4];
        tile[r][c4 + 0] = v.x;
        tile[r][c4 + 1] = v.y;
        tile[r][c4 + 2] = v.z;
        tile[r][c4 + 3] = v.w;
        __syncthreads();
        ushort4 o;
        o.x = f2bf(tile[c4 + 0][r]);
        o.y = f2bf(tile[c4 + 1][r]);
        o.z = f2bf(tile[c4 + 2][r]);
        o.w = f2bf(tile[c4 + 3][r]);
        *(ushort4*)&out[(size_t)(n0 + r) * C_DIM + k0 + c4] = o;
    }
}

// ---------------------------------------------------------------------------
// bf16 MFMA GEMM (R4/R6 proven config): 128x128 tile, 4 waves (2x2 of
// 64x64), 4x4 of 16x16x32 per wave, double-buffered global_load_lds staging
// of BOTH A and B, one barrier per K-iter.
// mode 0 (z 0..2): q (pre-scaled 0.125/ln2) / k bf16 [bh][t][d], v [bh][d][t]
// mode 1: fp32 [m][768] + bias
// ---------------------------------------------------------------------------
__global__ __launch_bounds__(256) void gemm_bf16(
    const unsigned short* __restrict__ A, const unsigned short* __restrict__ WtAll,
    const float* __restrict__ b0, const float* __restrict__ b1,
    const float* __restrict__ b2,
    unsigned short* __restrict__ qg, unsigned short* __restrict__ kg,
    unsigned short* __restrict__ vtg, float* __restrict__ outF, int mode)
{
    __shared__ __align__(16) unsigned short As[2][8 * 512];
    __shared__ __align__(16) unsigned short Bs[2][8 * 512];
    const int tid = threadIdx.x;
    const int lane = tid & 63, w = tid >> 6;
    const int L15 = lane & 15, quad = lane >> 4;
    const int m0 = blockIdx.x * 128, n0 = blockIdx.y * 128;
    const int z = blockIdx.z;
    const unsigned short* W = WtAll + (size_t)z * WSZ;

    const int c0 = 2 * w, c1 = 2 * w + 1;
    const size_t aOff0 = (size_t)(m0 + c0 * 16 + L15) * C_DIM + quad * 8;
    const size_t aOff1 = (size_t)(m0 + c1 * 16 + L15) * C_DIM + quad * 8;
    const size_t bOff0 = (size_t)(n0 + c0 * 16 + L15) * C_DIM + quad * 8;
    const size_t bOff1 = (size_t)(n0 + c1 * 16 + L15) * C_DIM + quad * 8;

    f32x4 acc[4][4];
#pragma unroll
    for (int i = 0; i < 4; i++)
#pragma unroll
        for (int j = 0; j < 4; j++) acc[i][j] = 0.0f;

    const int cm = (w >> 1) * 4, cn = (w & 1) * 4;

    gl2lds16(&A[aOff0], &As[0][c0 * 512]);
    gl2lds16(&A[aOff1], &As[0][c1 * 512]);
    gl2lds16(&W[bOff0], &Bs[0][c0 * 512]);
    gl2lds16(&W[bOff1], &Bs[0][c1 * 512]);
    __syncthreads();

    for (int kt = 0; kt < 24; kt++) {
        const int cur = kt & 1;
        if (kt < 23) {
            const size_t o = (size_t)(kt + 1) * 32;
            gl2lds16(&A[aOff0 + o], &As[cur ^ 1][c0 * 512]);
            gl2lds16(&A[aOff1 + o], &As[cur ^ 1][c1 * 512]);
            gl2lds16(&W[bOff0 + o], &Bs[cur ^ 1][c0 * 512]);
            gl2lds16(&W[bOff1 + o], &Bs[cur ^ 1][c1 * 512]);
        }
        bf16x8 aF[4], bF[4];
#pragma unroll
        for (int i = 0; i < 4; i++)
            aF[i] = *(const bf16x8*)&As[cur][(cm + i) * 512 + lane * 8];
#pragma unroll
        for (int j = 0; j < 4; j++)
            bF[j] = *(const bf16x8*)&Bs[cur][(cn + j) * 512 + lane * 8];
#pragma unroll
        for (int i = 0; i < 4; i++)
#pragma unroll
            for (int j = 0; j < 4; j++)
                acc[i][j] = __builtin_amdgcn_mfma_f32_16x16x32_bf16(
                    aF[i], bF[j], acc[i][j], 0, 0, 0);
        __syncthreads();
    }

    const float* bias = (mode == 0) ? ((z == 0) ? b0 : (z == 1) ? b1 : b2) : b0;
    // Q pre-scale folds 1/sqrt(64) and 1/ln(2) (attn exponentiates base-2)
    const float qscale = (z == 0 && mode == 0) ? 0.18033688011112042f : 1.0f;
#pragma unroll
    for (int i = 0; i < 4; i++) {
        const int mBase = m0 + (w >> 1) * 64 + i * 16 + quad * 4;
#pragma unroll
        for (int j = 0; j < 4; j++) {
            const int n = n0 + (w & 1) * 64 + j * 16 + L15;
            const float bn = bias[n];
            if (mode == 0) {
                const int h = n >> 6, d = n & 63;
                const int b = mBase >> 11, tB = mBase & (T_LEN - 1);
                if (z < 2) {
                    unsigned short* o = (z == 0) ? qg : kg;
#pragma unroll
                    for (int r = 0; r < 4; r++)
                        o[(((size_t)(b * NH + h)) * T_LEN + tB + r) * HD + d] =
                            f2bf((acc[i][j][r] + bn) * qscale);
                } else {
                    ushort4 o4;
                    o4.x = f2bf(acc[i][j][0] + bn);
                    o4.y = f2bf(acc[i][j][1] + bn);
                    o4.z = f2bf(acc[i][j][2] + bn);
                    o4.w = f2bf(acc[i][j][3] + bn);
                    *(ushort4*)&vtg[(((size_t)(b * NH + h)) * HD + d) * T_LEN + tB] = o4;
                }
            } else {
#pragma unroll
                for (int r = 0; r < 4; r++)
                    outF[(size_t)(mBase + r) * C_DIM + n] = acc[i][j][r] + bn;
            }
        }
    }
}

// ---------------------------------------------------------------------------
// MFMA flash attention (R6 proven config). 4 waves x 32 q = 128 q per block,
// 256 threads, grid 768. K AND V staged via dbuf global_load_lds.
// S^T = K·Q^T (32x32x16): lane owns one q, keys on regs. No-max softmax
// (p = 2^s, Q pre-scaled 0.125/ln2), l reduced once at the end.
// Register P-transpose via shfl_xor(32). LPT: heavy q-tiles first.
// ---------------------------------------------------------------------------
__global__ __launch_bounds__(256) void attn_mfma(
    const unsigned short* __restrict__ qg, const unsigned short* __restrict__ kg,
    const unsigned short* __restrict__ vtg, unsigned short* __restrict__ attb)
{
    __shared__ __align__(16) unsigned short Ks[2][8 * CH];
    __shared__ __align__(16) unsigned short Vs[2][8 * CH];
    const int tid = threadIdx.x;
    const int lane = tid & 63, w = tid >> 6;
    const int L15 = lane & 15, L31 = lane & 31;
    const int quad = lane >> 4, r4 = (lane >> 4) & 1, r5 = lane >> 5;

    // LPT: heaviest q-tiles dispatch first
    const int n = blockIdx.x;
    const int qi = 15 - (n / (B_SZ * NH));
    const int bh = n % (B_SZ * NH);
    const size_t base = (size_t)bh * T_LEN * HD;
    const int q0 = qi * 128;
    const int nk = 2 * qi + 2;
    const int qrow = q0 + w * 32 + L31;

    // Q fragments (B-operand): n=q on lane&31, k = r5*8+j per 16-d chunk
    bf16x8 qf[4];
#pragma unroll
    for (int kc = 0; kc < 4; kc++)
        qf[kc] = *(const bf16x8*)&qg[base + (size_t)qrow * HD + kc * 16 + r5 * 8];

    f32x16 accO[2];
#pragma unroll
    for (int md = 0; md < 2; md++) accO[md] = 0.0f;
    float l = 0.0f;

    auto stage = [&](int kt, int buf) {
        const int ktb = kt * 64;
        gl2lds16(&kg[base + (size_t)(ktb + w * 16 + L15) * HD + quad * 8],
                 &Ks[buf][(2 * w) * CH]);
        gl2lds16(&kg[base + (size_t)(ktb + w * 16 + L15) * HD + 32 + quad * 8],
                 &Ks[buf][(2 * w + 1) * CH]);
        gl2lds16(&vtg[base + (size_t)(w * 16 + L15) * T_LEN + ktb + quad * 8],
                 &Vs[buf][(2 * w) * CH]);
        gl2lds16(&vtg[base + (size_t)(w * 16 + L15) * T_LEN + ktb + 32 + quad * 8],
                 &Vs[buf][(2 * w + 1) * CH]);
    };

    stage(0, 0);
    __syncthreads();

    const int qmaxw = q0 + w * 32 + 31;
    const int qminw = q0 + w * 32;

    for (int kt = 0; kt < nk; kt++) {
        const int cur = kt & 1;
        if (kt + 1 < nk) stage(kt + 1, cur ^ 1);
        const int ktb = kt * 64;
        if (ktb <= qmaxw) {
            // ---- scores S^T ----
            f32x16 sa[2];
#pragma unroll
            for (int mi = 0; mi < 2; mi++) {
                sa[mi] = 0.0f;
#pragma unroll
                for (int kc = 0; kc < 4; kc++) {
                    const int ck = mi * 4 + r4 * 2 + (kc >> 1);
                    const int slot = L15 + 16 * ((kc & 1) * 2 + r5);
                    bf16x8 kf = *(const bf16x8*)&Ks[cur][ck * CH + slot * 8];
                    sa[mi] = __builtin_amdgcn_mfma_f32_32x32x16_bf16(
                        kf, qf[kc], sa[mi], 0, 0, 0);
                }
            }
            // ---- softmax (one q per lane) + register P-transpose ----
            const bool needmask = (ktb + 63 > qminw);
            bf16x8 pf[4];
#pragma unroll
            for (int mi = 0; mi < 2; mi++) {
                uint2 pk[4];  // pA..pD: keys {0-3,8-11,16-19,24-27}+4*r5
#pragma unroll
                for (int g = 0; g < 4; g++) {
                    float p[4];
#pragma unroll
                    for (int rr = 0; rr < 4; rr++) {
                        float s = sa[mi][g * 4 + rr];
                        if (needmask) {
                            const int key = ktb + mi * 32 + 8 * g + 4 * r5 + rr;
                            s = (key <= qrow) ? s : -1e30f;
                        }
                        p[rr] = fast_exp2(s);
                        l += p[rr];
                    }
                    pk[g].x = pk2bf(p[0], p[1]);
                    pk[g].y = pk2bf(p[2], p[3]);
                }
                // offer partner what it needs: r5=1 offers pA/pC, r5=0 offers pB/pD
                uint2 z1, z2, x1, x2;
                z1.x = r5 ? pk[0].x : pk[1].x;
                z1.y = r5 ? pk[0].y : pk[1].y;
                z2.x = r5 ? pk[2].x : pk[3].x;
                z2.y = r5 ? pk[2].y : pk[3].y;
                x1.x = (unsigned)__shfl_xor((int)z1.x, 32, 64);
                x1.y = (unsigned)__shfl_xor((int)z1.y, 32, 64);
                x2.x = (unsigned)__shfl_xor((int)z2.x, 32, 64);
                x2.y = (unsigned)__shfl_xor((int)z2.y, 32, 64);
                union { bf16x8 v; unsigned u[4]; } f0, f1;
                f0.u[0] = r5 ? x1.x : pk[0].x;
                f0.u[1] = r5 ? x1.y : pk[0].y;
                f0.u[2] = r5 ? pk[1].x : x1.x;
                f0.u[3] = r5 ? pk[1].y : x1.y;
                f1.u[0] = r5 ? x2.x : pk[2].x;
                f1.u[1] = r5 ? x2.y : pk[2].y;
                f1.u[2] = r5 ? pk[3].x : x2.x;
                f1.u[3] = r5 ? pk[3].y : x2.y;
                pf[mi * 2] = f0.v;
                pf[mi * 2 + 1] = f1.v;
            }
            // ---- O^T += V^T · P^T ----
#pragma unroll
            for (int md = 0; md < 2; md++) {
#pragma unroll
                for (int kc = 0; kc < 4; kc++) {
                    const int cv = md * 4 + r4 * 2 + (kc >> 1);
                    const int slot = L15 + 16 * ((kc & 1) * 2 + r5);
                    bf16x8 vf = *(const bf16x8*)&Vs[cur][cv * CH + slot * 8];
                    accO[md] = __builtin_amdgcn_mfma_f32_32x32x16_bf16(
                        vf, pf[kc], accO[md], 0, 0, 0);
                }
            }
        }
        __syncthreads();
    }

    // ---- epilogue: l reduce (r5 pair per q), normalize, store bf16 ----
    const float lt = l + __shfl_xor(l, 32, 64);
    const float inv = __builtin_amdgcn_rcpf(lt);
    const int b = bh / NH, h = bh % NH;
    const size_t orow = ((size_t)(b * T_LEN + qrow)) * C_DIM + h * HD;
#pragma unroll
    for (int md = 0; md < 2; md++) {
#pragma unroll
        for (int g = 0; g < 4; g++) {
            uint2 wv;
            wv.x = pk2bf(accO[md][g * 4 + 0] * inv, accO[md][g * 4 + 1] * inv);
            wv.y = pk2bf(accO[md][g * 4 + 2] * inv, accO[md][g * 4 + 3] * inv);
            *(uint2*)&attb[orow + md * 32 + 8 * g + 4 * r5] = wv;
        }
    }
}

extern "C" void kernel_launch(void* const* d_in, const int* in_sizes, int n_in,
                              void* d_out, int out_size, void* d_ws, size_t ws_size,
                              hipStream_t stream)
{
    const float* x  = (const float*)d_in[0];
    const float* Wq = (const float*)d_in[1];
    const float* bq = (const float*)d_in[2];
    const float* Wk = (const float*)d_in[3];
    const float* bk = (const float*)d_in[4];
    const float* Wv = (const float*)d_in[5];
    const float* bv = (const float*)d_in[6];
    const float* Wo = (const float*)d_in[7];
    const float* bo = (const float*)d_in[8];
    float* out = (float*)d_out;

    const size_t nMC = (size_t)M_ROWS * C_DIM;  // 6291456
    unsigned short* xb   = (unsigned short*)d_ws;
    unsigned short* Wt   = xb + nMC;
    unsigned short* qg   = Wt + 4 * (size_t)WSZ;
    unsigned short* kg   = qg + nMC;
    unsigned short* vtg  = kg + nMC;
    unsigned short* attb = vtg + nMC;

    prep<<<6144 + 2304, 256, 0, stream>>>(x, Wq, Wk, Wv, Wo, xb, Wt);
    gemm_bf16<<<dim3(64, 6, 3), 256, 0, stream>>>(xb, Wt, bq, bk, bv,
                                                  qg, kg, vtg, nullptr, 0);
    attn_mfma<<<16 * B_SZ * NH, 256, 0, stream>>>(qg, kg, vtg, attb);
    gemm_bf16<<<dim3(64, 6, 1), 256, 0, stream>>>(attb, Wt + 3 * (size_t)WSZ,
                                                  bo, bo, bo, nullptr, nullptr,
                                                  nullptr, out, 1);
}